// Round 1
// 230.793 us; speedup vs baseline: 1.0613x; 1.0613x over previous
//
#include <hip/hip_runtime.h>
#include <hip/hip_bf16.h>
#include <math.h>

typedef unsigned short ushort_t;
typedef unsigned char uchar_t;
typedef unsigned int uint_t;
typedef __attribute__((ext_vector_type(8))) short bf16x8;   // 8 bf16 = 4 VGPRs
typedef __attribute__((ext_vector_type(4))) float f32x4;

#define AS1 __attribute__((address_space(1)))
#define AS3 __attribute__((address_space(3)))

__device__ __forceinline__ void gld_lds16(const void* g, void* l) {
  // async global->LDS, 16B per lane; LDS dest = wave-uniform base + lane*16
  __builtin_amdgcn_global_load_lds((const AS1 void*)g, (AS3 void*)l, 16, 0, 0);
}

__device__ __forceinline__ ushort_t f32_to_bf16_bits(float v) {
  __hip_bfloat16 b = __float2bfloat16(v);
  return *(ushort_t*)&b;
}

__device__ __forceinline__ uint_t pack_fp8x4(float4 v, float sc) {
  int r = __builtin_amdgcn_cvt_pk_fp8_f32(v.x * sc, v.y * sc, 0, false);
  r = __builtin_amdgcn_cvt_pk_fp8_f32(v.z * sc, v.w * sc, r, true);
  return (uint_t)r;
}

// ================= tiled operand layout =================
// Unit tile = 16 rows x 64 B, stored contiguously (1024 B). Tile index =
// rowblock * nKtiles + kt. Within a tile row rl, the 64 B is split into chunks
// XOR-permuted by a per-row key so MFMA fragment ds_reads are conflict-free:
//   fp8  (8-B chunks):  phys = logical ^ ((rl>>1)&7)   [R5: conflicts -> 0]
//   bf16 (16-B chunks): phys = logical ^ ((rl>>1)&3)   [2-way floor, free]
// global_load_lds copies tiles verbatim, so the LDS image equals the global image.

// ---------------- single prep kernel ----------------
__global__ __launch_bounds__(256) void prep(const float4* __restrict__ h,
                                            uchar_t* __restrict__ h8, int rowsH,
                                            const float4* __restrict__ p,
                                            uchar_t* __restrict__ p8, int rowsP,
                                            const float* __restrict__ pc,
                                            ushort_t* __restrict__ pcT,
                                            int P, int C, int normBlocks) {
  __shared__ float tile[32][33];
  if ((int)blockIdx.x < normBlocks) {
    int r = (blockIdx.x * 256 + threadIdx.x) >> 6;
    const int lane = threadIdx.x & 63;
    const float4* xr;
    uchar_t* o8;
    if (r < rowsH) {
      xr = h + (size_t)r * 192;          // 768 floats = 192 float4
      o8 = h8;
    } else {
      r -= rowsH;
      if (r >= rowsP) return;
      xr = p + (size_t)r * 192;
      o8 = p8;
    }
    float4 v0 = xr[lane];
    float4 v1 = xr[lane + 64];
    float4 v2 = xr[lane + 128];
    float ss = v0.x * v0.x + v0.y * v0.y + v0.z * v0.z + v0.w * v0.w
             + v1.x * v1.x + v1.y * v1.y + v1.z * v1.z + v1.w * v1.w
             + v2.x * v2.x + v2.y * v2.y + v2.z * v2.z + v2.w * v2.w;
#pragma unroll
    for (int off = 32; off > 0; off >>= 1) ss += __shfl_xor(ss, off, 64);
    const float sc = 4.0f / fmaxf(sqrtf(ss), 1e-12f);
    // lane L holds elements 4L..4L+3 of each 256-element group
    const int rb = r >> 4, rl = r & 15;
    const int key = (rl >> 1) & 7;
    const int cc = (lane & 15) >> 1;                  // logical 8-B chunk
    const int cphys = ((cc ^ key) << 3) + ((lane & 1) << 2);
    const int ktb = lane >> 4;                        // tile within group
    uchar_t* rowbase = o8 + (size_t)rb * 12 * 1024 + rl * 64 + cphys;
    *(uint_t*)(rowbase + (size_t)(ktb) * 1024)     = pack_fp8x4(v0, sc);
    *(uint_t*)(rowbase + (size_t)(4 + ktb) * 1024) = pack_fp8x4(v1, sc);
    *(uint_t*)(rowbase + (size_t)(8 + ktb) * 1024) = pack_fp8x4(v2, sc);
  } else {
    const int b = blockIdx.x - normBlocks;
    const int nkb = P / 32;                   // k-tiles per pcT row-block (=64)
    const int bk = b % nkb, bc = b / nkb;
    const int k0 = bk * 32, c0 = bc * 32;
    const int tx = threadIdx.x & 31, ty = threadIdx.x >> 5;   // ty 0..7
#pragma unroll
    for (int rr = 0; rr < 4; ++rr) {
      const int c = c0 + tx;
      tile[ty + rr * 8][tx] = (c < C) ? pc[(size_t)(k0 + ty + rr * 8) * C + c] : 0.f;
    }
    __syncthreads();
    const int c2 = tx >> 3, off = tx & 7;
#pragma unroll
    for (int rr = 0; rr < 4; ++rr) {
      const int row = c0 + ty + rr * 8;       // pcT row (class dim)
      const int rb = row >> 4, rl = row & 15;
      const int key4 = (rl >> 1) & 3;
      size_t us = (((size_t)rb * nkb + bk) * 16 + rl) * 32 + ((c2 ^ key4) << 3) + off;
      pcT[us] = f32_to_bf16_bits(tile[tx][ty + rr * 8]);
    }
  }
}

// ---------------- GEMM1: 128x128 fp8 MFMA, BK=128 (6 iters), tiled, XCD-swizzled ----------------
// act[N,P](bf16 tiled) = epilogue( h8 @ p8^T ), fp8 e4m3 scale x4 (acc = 16*dot).
__launch_bounds__(256)
__global__ void gemm1_fp8(const uchar_t* __restrict__ A, const uchar_t* __restrict__ B,
                          ushort_t* __restrict__ act, const float* __restrict__ tptr,
                          int nKt, int actKT, int gx, int gxlog2) {
  __shared__ __align__(16) uchar_t As[16384];   // 8 row-tiles x 2 k-tiles x 1 KB
  __shared__ __align__(16) uchar_t Bs[16384];
  const int tid = threadIdx.x, lane = tid & 63, wave = tid >> 6;
  const int wm = wave >> 1, wn = wave & 1;      // 2x2 wave grid, 64x64 each
  const int lid = blockIdx.x, xcd = lid & 7, q = lid >> 3;
  const int t = q & (gx - 1);
  const int s = ((q >> gxlog2) << 3) | xcd;

  f32x4 acc[4][4];
#pragma unroll
  for (int i = 0; i < 4; ++i)
#pragma unroll
    for (int j = 0; j < 4; ++j) acc[i][j] = (f32x4){0.f, 0.f, 0.f, 0.f};

  // staging: wave covers row-tiles {2w,2w+1} x k-tiles {2kt,2kt+1}; 1 KB per call
  const uchar_t* aW = A + ((size_t)(s * 8 + 2 * wave) * nKt) * 1024 + lane * 16;
  const uchar_t* bW = B + ((size_t)(t * 8 + 2 * wave) * nKt) * 1024 + lane * 16;
  const size_t rstride = (size_t)nKt * 1024;
  uchar_t* lA = &As[wave * 4096];
  uchar_t* lB = &Bs[wave * 4096];

  const int fr = lane & 15, g = lane >> 4;
  const int key = (fr >> 1) & 7;
  const int rowoff = fr * 64;
  const int cp0 = ((g ^ key) << 3);             // ksub=0: logical chunk g
  const int cp1 = (((g | 4) ^ key) << 3);       // ksub=1: logical chunk g+4

  const int nIter = nKt >> 1;                   // 6
  for (int kt = 0; kt < nIter; ++kt) {
    const size_t koff = (size_t)(2 * kt) * 1024;
    __syncthreads();  // previous tile's LDS reads done
    gld_lds16(aW + koff, lA);
    gld_lds16(aW + koff + 1024, lA + 1024);
    gld_lds16(aW + rstride + koff, lA + 2048);
    gld_lds16(aW + rstride + koff + 1024, lA + 3072);
    gld_lds16(bW + koff, lB);
    gld_lds16(bW + koff + 1024, lB + 1024);
    gld_lds16(bW + rstride + koff, lB + 2048);
    gld_lds16(bW + rstride + koff + 1024, lB + 3072);
    __syncthreads();  // staging complete

#pragma unroll
    for (int kk = 0; kk < 2; ++kk) {
#pragma unroll
      for (int ksub = 0; ksub < 2; ++ksub) {
        const int cp = ksub ? cp1 : cp0;
        long a[4], b[4];
#pragma unroll
        for (int i = 0; i < 4; ++i)
          a[i] = *(const long*)&As[((wm * 4 + i) * 2 + kk) * 1024 + rowoff + cp];
#pragma unroll
        for (int j = 0; j < 4; ++j)
          b[j] = *(const long*)&Bs[((wn * 4 + j) * 2 + kk) * 1024 + rowoff + cp];
#pragma unroll
        for (int i = 0; i < 4; ++i)
#pragma unroll
          for (int j = 0; j < 4; ++j)
            acc[i][j] = __builtin_amdgcn_mfma_f32_16x16x32_fp8_fp8(a[i], b[j], acc[i][j], 0, 0, 0);
      }
    }
  }

  float tmp = *tptr;
  const float tau = log1pf(expf(tmp));
  // C/D layout: col = lane&15, row = (lane>>4)*4 + reg   [measured m89/m91]
  const int crow = g * 4, ccol = fr;
  const int rowB = s * 128 + wm * 64, colB = t * 128 + wn * 64;
#pragma unroll
  for (int i = 0; i < 4; ++i)
#pragma unroll
    for (int j = 0; j < 4; ++j) {
      const int col = colB + j * 16 + ccol;
      const size_t ktile = col >> 5;
      const int c2 = (col >> 3) & 3, co = col & 7;
#pragma unroll
      for (int rr = 0; rr < 4; ++rr) {
        const int row = rowB + i * 16 + crow + rr;
        const int rb = row >> 4, rl = row & 15;
        const int key4 = (rl >> 1) & 3;
        float d2 = fmaxf(2.0f - acc[i][j][rr] * 0.125f, 0.0f);   // acc = 16*dot
        float a = __expf(-tau * sqrtf(d2));
        act[(((size_t)rb * actKT + ktile) * 16 + rl) * 32 + ((c2 ^ key4) << 3) + co] =
            f32_to_bf16_bits(a);
      }
    }
}

// ---------------- GEMM2: 256x256 bf16 MFMA, 8-phase counted-vmcnt schedule ----------------
// out[N,C](f32) = act @ pcT^T.  BM=BN=256, BK=64, 8 waves (2Mx4N), per-wave 128x64.
// LDS 128 KiB = 2 dbuf x (A 32K + B 32K); K-tile = 32 unit tiles per operand.
// Per K-tile: 4 phases {ds_read (A-pair; +all B in ph1) | stage 1 half-tile (2 gld/wave)
//   | barrier | lgkmcnt(0) | setprio(1) 16 MFMA setprio(0) | [ph4: vmcnt(6)] | barrier}.
// Half-tile issue order for tile T: h0=B[0-7] @T-2.ph2, h1=B[8-15] @T-2.ph3,
//   h2=A{0-3,8-11} @T-2.ph4, h3=A{4-7,12-15} @T-1.ph1.  vmcnt(6) at ph4 = 3 half-tiles
//   in flight -> tile T+1 fully landed (verified disjoint from all live read regions).
#define BARRIER() do { asm volatile("" ::: "memory"); __builtin_amdgcn_s_barrier(); \
                       asm volatile("" ::: "memory"); } while (0)
#define LGKM0()   asm volatile("s_waitcnt lgkmcnt(0)" ::: "memory")
#define VM6()     asm volatile("s_waitcnt vmcnt(6)" ::: "memory")
#define VM0()     asm volatile("s_waitcnt vmcnt(0)" ::: "memory")
#define PRIO1()   __builtin_amdgcn_s_setprio(1)
#define PRIO0()   __builtin_amdgcn_s_setprio(0)
#define MM(a, b, c) __builtin_amdgcn_mfma_f32_16x16x32_bf16(a, b, c, 0, 0, 0)

// 16 MFMA for fragment rows I0,I1 over K=64 (l=0 then l=1; same-acc distance 8)
#define PHASE_MFMA(I0, I1, A00, A01, A10, A11)                                   \
  acc[I0][0] = MM(A00, b00, acc[I0][0]); acc[I0][1] = MM(A00, b10, acc[I0][1]);  \
  acc[I0][2] = MM(A00, b20, acc[I0][2]); acc[I0][3] = MM(A00, b30, acc[I0][3]);  \
  acc[I1][0] = MM(A10, b00, acc[I1][0]); acc[I1][1] = MM(A10, b10, acc[I1][1]);  \
  acc[I1][2] = MM(A10, b20, acc[I1][2]); acc[I1][3] = MM(A10, b30, acc[I1][3]);  \
  acc[I0][0] = MM(A01, b01, acc[I0][0]); acc[I0][1] = MM(A01, b11, acc[I0][1]);  \
  acc[I0][2] = MM(A01, b21, acc[I0][2]); acc[I0][3] = MM(A01, b31, acc[I0][3]);  \
  acc[I1][0] = MM(A11, b01, acc[I1][0]); acc[I1][1] = MM(A11, b11, acc[I1][1]);  \
  acc[I1][2] = MM(A11, b21, acc[I1][2]); acc[I1][3] = MM(A11, b31, acc[I1][3])

__launch_bounds__(512, 2)
__global__ void gemm2_bf16_8ph(const ushort_t* __restrict__ A,
                               const ushort_t* __restrict__ B,
                               float* __restrict__ out, int ldc, int ncols,
                               int nKt) {
  __shared__ __align__(16) uchar_t sm[131072];
  const int tid = threadIdx.x, lane = tid & 63, wave = tid >> 6;   // 8 waves
  const int wm = wave >> 2, wn = wave & 3;                         // 2M x 4N
  const int lid = blockIdx.x, xcd = lid & 7, q = lid >> 3;
  const int tb = q & 3, sb = ((q >> 2) << 3) | xcd;   // col-tile 0..3, row-tile 0..63

  f32x4 acc[8][4];
#pragma unroll
  for (int i = 0; i < 8; ++i)
#pragma unroll
    for (int j = 0; j < 4; ++j) acc[i][j] = (f32x4){0.f, 0.f, 0.f, 0.f};

  // stage-role: wave pair rw = wave>>1 covers row-blocks {rw, rw+4, rw+8, rw+12},
  // lw = wave&1 selects the unit-k (l) within the K-tile.
  const int lw = wave & 1, rw = wave >> 1;
  const uchar_t* Apl = (const uchar_t*)A + ((size_t)(sb * 16) << 16) + (lw << 10) + lane * 16;
  const uchar_t* Bpl = (const uchar_t*)B + ((size_t)(tb * 16) << 16) + (lw << 10) + lane * 16;

  // ds_read per-lane offset within a unit tile (16-B chunk XOR key)
  const int fr = lane & 15, g = lane >> 4;
  const int rdoff = fr * 64 + ((g ^ ((fr >> 1) & 3)) << 4);
  const int wm8 = wm * 8, wn4 = wn * 4;

#define STA(r_, T_, bo_) gld_lds16(Apl + (((size_t)(r_) << 16) + ((size_t)(T_) << 11)), \
                                   sm + (bo_) + ((((r_) << 1) + lw) << 10))
#define STB(r_, T_, bo_) gld_lds16(Bpl + (((size_t)(r_) << 16) + ((size_t)(T_) << 11)), \
                                   sm + (bo_) + 32768 + ((((r_) << 1) + lw) << 10))
#define DSA(i_, l_) (*(const bf16x8*)(sm + bufoff + (((wm8 + (i_)) * 2 + (l_)) << 10) + rdoff))
#define DSB(j_, l_) (*(const bf16x8*)(sm + bufoff + 32768 + (((wn4 + (j_)) * 2 + (l_)) << 10) + rdoff))

  // prologue: tile 0 fully (8 calls, oldest), tile 1 h0..h2 (6 calls)
  STB(rw, 0, 0); STB(rw + 4, 0, 0); STB(rw + 8, 0, 0); STB(rw + 12, 0, 0);
  STA(rw, 0, 0); STA(rw + 8, 0, 0); STA(rw + 4, 0, 0); STA(rw + 12, 0, 0);
  STB(rw, 1, 65536); STB(rw + 4, 1, 65536); STB(rw + 8, 1, 65536); STB(rw + 12, 1, 65536);
  STA(rw, 1, 65536); STA(rw + 8, 1, 65536);
  VM6(); BARRIER();

  for (int kt = 0; kt < nKt; ++kt) {
    const int bufoff = (kt & 1) << 16;
    const int nbo = ((kt + 1) & 1) << 16;
    // ---------- phase 1: all B + A rows 0,1 (12 reads); stage (kt+1) h3 ----------
    bf16x8 b00 = DSB(0, 0), b01 = DSB(0, 1), b10 = DSB(1, 0), b11 = DSB(1, 1);
    bf16x8 b20 = DSB(2, 0), b21 = DSB(2, 1), b30 = DSB(3, 0), b31 = DSB(3, 1);
    bf16x8 a00 = DSA(0, 0), a01 = DSA(0, 1), a10 = DSA(1, 0), a11 = DSA(1, 1);
    if (kt + 1 < nKt) { STA(rw + 4, kt + 1, nbo); STA(rw + 12, kt + 1, nbo); }
    BARRIER(); LGKM0();
    PRIO1();
    PHASE_MFMA(0, 1, a00, a01, a10, a11);
    PRIO0();
    BARRIER();
    // ---------- phase 2: A rows 2,3; stage (kt+2) h0 = B[0-7] ----------
    {
      bf16x8 a20 = DSA(2, 0), a21 = DSA(2, 1), a30 = DSA(3, 0), a31 = DSA(3, 1);
      if (kt + 2 < nKt) { STB(rw, kt + 2, bufoff); STB(rw + 4, kt + 2, bufoff); }
      BARRIER(); LGKM0();
      PRIO1();
      PHASE_MFMA(2, 3, a20, a21, a30, a31);
      PRIO0();
      BARRIER();
    }
    // ---------- phase 3: A rows 4,5; stage (kt+2) h1 = B[8-15] ----------
    {
      bf16x8 a40 = DSA(4, 0), a41 = DSA(4, 1), a50 = DSA(5, 0), a51 = DSA(5, 1);
      if (kt + 2 < nKt) { STB(rw + 8, kt + 2, bufoff); STB(rw + 12, kt + 2, bufoff); }
      BARRIER(); LGKM0();
      PRIO1();
      PHASE_MFMA(4, 5, a40, a41, a50, a51);
      PRIO0();
      BARRIER();
    }
    // ---------- phase 4: A rows 6,7; stage (kt+2) h2 = A{0-3,8-11}; counted vmcnt ----------
    {
      bf16x8 a60 = DSA(6, 0), a61 = DSA(6, 1), a70 = DSA(7, 0), a71 = DSA(7, 1);
      if (kt + 2 < nKt) { STA(rw, kt + 2, bufoff); STA(rw + 8, kt + 2, bufoff); }
      BARRIER(); LGKM0();
      PRIO1();
      PHASE_MFMA(6, 7, a60, a61, a70, a71);
      PRIO0();
      if (kt + 2 < nKt) { VM6(); } else { VM0(); }
      BARRIER();
    }
  }

  // epilogue: C/D layout col = lane&15, row = (lane>>4)*4 + reg
  const int crow = g * 4;
  const int rowB = sb * 256 + wm * 128, colB = tb * 256 + wn * 64;
#pragma unroll
  for (int i = 0; i < 8; ++i)
#pragma unroll
    for (int j = 0; j < 4; ++j) {
      const int col = colB + j * 16 + fr;
      if (col < ncols) {
#pragma unroll
        for (int rr = 0; rr < 4; ++rr)
          out[(size_t)(rowB + i * 16 + crow + rr) * ldc + col] = acc[i][j][rr];
      }
    }
}

extern "C" void kernel_launch(void* const* d_in, const int* in_sizes, int n_in,
                              void* d_out, int out_size, void* d_ws, size_t ws_size,
                              hipStream_t stream) {
  const float* h    = (const float*)d_in[0];
  const float* prot = (const float*)d_in[1];
  const float* pc   = (const float*)d_in[2];
  const float* temp = (const float*)d_in[3];
  float* out = (float*)d_out;

  const int D = 768;
  const int N = in_sizes[0] / D;          // 16384
  const int P = in_sizes[1] / D;          // 2048
  const int C = in_sizes[2] / P;          // 1000
  const int CP = (C + 127) & ~127;        // 1024 (padded)

  // workspace layout (16B aligned), all tiled
  char* ws = (char*)d_ws;
  size_t off = 0;
  uchar_t* h8   = (uchar_t*)(ws + off); off += (size_t)N * D;         // 12.6 MB fp8
  uchar_t* p8   = (uchar_t*)(ws + off); off += (size_t)P * D;         //  1.6 MB fp8
  ushort_t* pcT = (ushort_t*)(ws + off); off += (size_t)CP * P * 2;   //  4.2 MB bf16
  ushort_t* act = (ushort_t*)(ws + off); off += (size_t)N * P * 2;    // 67.1 MB bf16
  (void)ws_size;  // total ~85.5 MB

  // single prep dispatch: normalize (fp8 x4, tiled) + transpose (bf16, tiled)
  const int normBlocks = (N + P) / 4;                 // 4608
  const int transBlocks = (P / 32) * (CP / 32);       // 2048
  prep<<<normBlocks + transBlocks, 256, 0, stream>>>(
      (const float4*)h, h8, N, (const float4*)prot, p8, P,
      pc, pcT, P, C, normBlocks);

  // GEMM1: act[N,P](bf16 tiled) = epilogue(h8 @ p8^T), fp8, BK=128
  {
    const int GX = P / 128, GY = N / 128;   // 16, 128
    gemm1_fp8<<<GX * GY, 256, 0, stream>>>(h8, p8, act, temp, D / 64, P / 32, GX, 4);
  }
  // GEMM2: out[N,C](f32) = act @ pcT^T, bf16, 256^2 8-phase counted-vmcnt
  {
    const int GX = CP / 256, GY = N / 256;  // 4, 64  -> 256 blocks = 1/CU
    gemm2_bf16_8ph<<<GX * GY, 512, 0, stream>>>(act, pcT, out, C, C, P / 64);
  }
}